// Round 1
// baseline (334.988 us; speedup 1.0000x reference)
//
#include <hip/hip_runtime.h>
#include <hip/hip_bf16.h>

#define Bb 512
#define Tt 512
#define Kk 64
#define START_TAG 62
#define STOP_TAG 63

// Forward algorithm in exp-space with running log-scale.
// One 64-lane wave per sequence. Lane i owns output tag i and holds
// eT[i][j] = exp(transitions[i*K+j]) in 64 VGPRs.
__global__ __launch_bounds__(64) void crf_forward_kernel(
    const float* __restrict__ feats,        // (B,T,K)
    const float* __restrict__ transitions,  // (K,K), trans[i,j] = score j->i
    const int* __restrict__ lengths,        // (B,)
    float* __restrict__ fwd_out)            // (B,)
{
    const int b = blockIdx.x;
    const int i = threadIdx.x;  // 0..63
    __shared__ __align__(16) float sa[Kk];

    // exp of transitions row i (into-tag i). expf(-10000) == 0 handles masking.
    float trow[Kk];
#pragma unroll
    for (int j = 0; j < Kk; ++j) trow[j] = expf(transitions[i * Kk + j]);
    const float etstop = expf(transitions[STOP_TAG * Kk + i]);

    const int len = lengths[b];
    const float* fb = feats + (size_t)b * Tt * Kk;

    float ea = (i == START_TAG) ? 1.0f : 0.0f;  // exp(alpha - s), s = 0
    float logscale = 0.0f;

    for (int t = 0; t < len; ++t) {
        const float emit = fb[t * Kk + i];  // coalesced 256B per wave
        sa[i] = ea;
        __syncthreads();
        float acc0 = 0.f, acc1 = 0.f, acc2 = 0.f, acc3 = 0.f;
#pragma unroll
        for (int j4 = 0; j4 < Kk / 4; ++j4) {
            const float4 a4 = *reinterpret_cast<const float4*>(&sa[j4 * 4]);
            acc0 = fmaf(a4.x, trow[j4 * 4 + 0], acc0);
            acc1 = fmaf(a4.y, trow[j4 * 4 + 1], acc1);
            acc2 = fmaf(a4.z, trow[j4 * 4 + 2], acc2);
            acc3 = fmaf(a4.w, trow[j4 * 4 + 3], acc3);
        }
        float p = (acc0 + acc1) + (acc2 + acc3);
        p *= expf(emit);
        // wave-max for rescale
        float m = p;
#pragma unroll
        for (int off = 32; off >= 1; off >>= 1)
            m = fmaxf(m, __shfl_xor(m, off, 64));
        ea = p / m;
        logscale += logf(m);
        __syncthreads();  // all lanes done reading sa before next overwrite
    }

    // terminal: logsumexp_i(alpha_i + T[STOP, i])
    float q = ea * etstop;
#pragma unroll
    for (int off = 32; off >= 1; off >>= 1) q += __shfl_xor(q, off, 64);
    if (i == 0) fwd_out[b] = logscale + logf(q);
}

// Gold path score: fully parallel over t (lane-strided).
__global__ __launch_bounds__(64) void crf_gold_kernel(
    const float* __restrict__ feats,
    const float* __restrict__ transitions,
    const int* __restrict__ tags,     // (B,T)
    const int* __restrict__ lengths,  // (B,)
    float* __restrict__ gold_out)     // (B,)
{
    const int b = blockIdx.x;
    const int lane = threadIdx.x;
    const int len = lengths[b];
    const int* tb = tags + b * Tt;
    const float* fb = feats + (size_t)b * Tt * Kk;

    float acc = 0.f;
    for (int t = lane; t < len; t += 64) {
        const int tg = tb[t];
        const int prev = (t == 0) ? START_TAG : tb[t - 1];
        acc += transitions[tg * Kk + prev];  // score prev -> tg
        acc += fb[t * Kk + tg];              // emission
    }
    if (lane == 0) acc += transitions[STOP_TAG * Kk + tb[len - 1]];  // last -> STOP
#pragma unroll
    for (int off = 32; off >= 1; off >>= 1) acc += __shfl_xor(acc, off, 64);
    if (lane == 0) gold_out[b] = acc;
}

__global__ __launch_bounds__(512) void crf_reduce_kernel(
    const float* __restrict__ fwd, const float* __restrict__ gold,
    float* __restrict__ out)
{
    const int i = threadIdx.x;  // 0..511
    float v = fwd[i] - gold[i];
#pragma unroll
    for (int off = 32; off >= 1; off >>= 1) v += __shfl_xor(v, off, 64);
    __shared__ float ws[8];
    if ((i & 63) == 0) ws[i >> 6] = v;
    __syncthreads();
    if (i < 8) {
        float s = ws[i];
#pragma unroll
        for (int off = 4; off >= 1; off >>= 1) s += __shfl_xor(s, off, 8);
        if (i == 0) out[0] = s * (1.0f / (float)Bb);
    }
}

extern "C" void kernel_launch(void* const* d_in, const int* in_sizes, int n_in,
                              void* d_out, int out_size, void* d_ws, size_t ws_size,
                              hipStream_t stream) {
    const float* feats = (const float*)d_in[0];
    const float* trans = (const float*)d_in[1];
    const int* tags = (const int*)d_in[2];
    const int* lengths = (const int*)d_in[3];
    float* out = (float*)d_out;
    float* fwd = (float*)d_ws;
    float* gold = fwd + Bb;

    crf_gold_kernel<<<Bb, 64, 0, stream>>>(feats, trans, tags, lengths, gold);
    crf_forward_kernel<<<Bb, 64, 0, stream>>>(feats, trans, lengths, fwd);
    crf_reduce_kernel<<<1, 512, 0, stream>>>(fwd, gold, out);
}

// Round 2
// 220.987 us; speedup vs baseline: 1.5159x; 1.5159x over previous
//
#include <hip/hip_runtime.h>
#include <hip/hip_bf16.h>

#define Bb 512
#define Tt 512
#define Kk 64
#define START_TAG 62
#define STOP_TAG 63
#define LN2F 0.69314718055994530942f

// Forward algorithm in exp-space, one 64-lane wave per sequence.
// Lane i owns output tag i; exp(transitions[i][:]) lives in 16 NAMED float4
// VGPR quads (T0..T15) — round 0's array version was demoted to scratch
// (VGPR_Count=60 proved it) and cost ~1600 cyc/step.
// Rescale every 4 steps by an exact power of two (exponent extraction, no
// logf/div in the loop); emits prefetched one group (4 steps) ahead.
__global__ __launch_bounds__(64) void crf_forward_kernel(
    const float* __restrict__ feats,        // (B,T,K)
    const float* __restrict__ transitions,  // (K,K), trans[i,j] = score j->i
    const int* __restrict__ lengths,        // (B,)
    float* __restrict__ fwd_out)            // (B,)
{
    const int b = blockIdx.x;
    const int i = threadIdx.x;  // 0..63
    __shared__ __align__(16) float sa[Kk];
    const float4* sa4 = reinterpret_cast<const float4*>(sa);

    const float4* tr4 = reinterpret_cast<const float4*>(transitions + i * Kk);
#define LOADT(n) float4 T##n = tr4[n];                                   \
    T##n.x = __expf(T##n.x); T##n.y = __expf(T##n.y);                    \
    T##n.z = __expf(T##n.z); T##n.w = __expf(T##n.w);
    LOADT(0)  LOADT(1)  LOADT(2)  LOADT(3)
    LOADT(4)  LOADT(5)  LOADT(6)  LOADT(7)
    LOADT(8)  LOADT(9)  LOADT(10) LOADT(11)
    LOADT(12) LOADT(13) LOADT(14) LOADT(15)
#undef LOADT
    const float etstop = __expf(transitions[STOP_TAG * Kk + i]);

    const int len = lengths[b];
    const float* fb = feats + (size_t)b * Tt * Kk + i;

    // init: exp(alpha) = 1 at START, 0 elsewhere; scale s = 0 (ktot=0)
    sa[i] = (i == START_TAG) ? 1.0f : 0.0f;
    __builtin_amdgcn_wave_barrier();

    int ktot = 0;        // applied log2-scale (integer, exact)
    float s_pend = 1.0f; // pending 2^-k, folded into next group's first emit
    float pcur = (i == START_TAG) ? 1.0f : 0.0f;  // lane-local copy of sa[i]

    // prefetch emits for t = 0..3 (always in-bounds: T = 512 rows per seq)
    float e0 = fb[0], e1 = fb[Kk], e2 = fb[2 * Kk], e3 = fb[3 * Kk];

    const int nfull = len & ~3;

#define MV4(n, A0, A1, A2, A3) { float4 a_ = sa4[n];                     \
    A0 = fmaf(a_.x, T##n.x, A0); A1 = fmaf(a_.y, T##n.y, A1);            \
    A2 = fmaf(a_.z, T##n.z, A2); A3 = fmaf(a_.w, T##n.w, A3); }

#define SUBSTEP(EE) {                                                    \
    float q0=0.f,q1=0.f,q2=0.f,q3=0.f,q4=0.f,q5=0.f,q6=0.f,q7=0.f;       \
    MV4(0,q0,q1,q2,q3)  MV4(1,q4,q5,q6,q7)                               \
    MV4(2,q0,q1,q2,q3)  MV4(3,q4,q5,q6,q7)                               \
    MV4(4,q0,q1,q2,q3)  MV4(5,q4,q5,q6,q7)                               \
    MV4(6,q0,q1,q2,q3)  MV4(7,q4,q5,q6,q7)                               \
    MV4(8,q0,q1,q2,q3)  MV4(9,q4,q5,q6,q7)                               \
    MV4(10,q0,q1,q2,q3) MV4(11,q4,q5,q6,q7)                              \
    MV4(12,q0,q1,q2,q3) MV4(13,q4,q5,q6,q7)                              \
    MV4(14,q0,q1,q2,q3) MV4(15,q4,q5,q6,q7)                              \
    pcur = (((q0+q1)+(q2+q3)) + ((q4+q5)+(q6+q7))) * (EE);               \
    sa[i] = pcur;                                                        \
    __builtin_amdgcn_wave_barrier(); }

    for (int t = 0; t < nfull; t += 4) {
        // emit exps off the critical path; fold pending scale into ee0
        float ee0 = __expf(e0) * s_pend;
        float ee1 = __expf(e1);
        float ee2 = __expf(e2);
        float ee3 = __expf(e3);
        // prefetch next group (clamped; values past len are never used)
        const int tn = t + 4;
        const int c0 = (tn     < Tt) ? tn     : Tt - 1;
        const int c1 = (tn + 1 < Tt) ? tn + 1 : Tt - 1;
        const int c2 = (tn + 2 < Tt) ? tn + 2 : Tt - 1;
        const int c3 = (tn + 3 < Tt) ? tn + 3 : Tt - 1;
        e0 = fb[c0 * Kk]; e1 = fb[c1 * Kk]; e2 = fb[c2 * Kk]; e3 = fb[c3 * Kk];

        SUBSTEP(ee0) SUBSTEP(ee1) SUBSTEP(ee2) SUBSTEP(ee3)

        // rescale by exact 2^-k, k = floor(log2(wave-max))
        float m = pcur;
        m = fmaxf(m, __shfl_xor(m, 1, 64));
        m = fmaxf(m, __shfl_xor(m, 2, 64));
        m = fmaxf(m, __shfl_xor(m, 4, 64));
        m = fmaxf(m, __shfl_xor(m, 8, 64));
        m = fmaxf(m, __shfl_xor(m, 16, 64));
        m = fmaxf(m, __shfl_xor(m, 32, 64));
        const int k = (int)((__float_as_uint(m) >> 23) & 255) - 127;
        ktot += k;
        s_pend = __uint_as_float((unsigned)(127 - k) << 23);
    }

    // tail (<= 3 steps; growth from max~2 stays < 1e19, safe without rescale)
    if (nfull < len) {
        float ee = __expf(e0) * s_pend;
        SUBSTEP(ee)
        s_pend = 1.0f;
        if (nfull + 1 < len) { float ee1 = __expf(e1); SUBSTEP(ee1) }
        if (nfull + 2 < len) { float ee2 = __expf(e2); SUBSTEP(ee2) }
    }

    // terminal: log sum_i exp(alpha_i) * eT[STOP,i]  (+ applied scales)
    float q = pcur * s_pend * etstop;
    q += __shfl_xor(q, 1, 64);
    q += __shfl_xor(q, 2, 64);
    q += __shfl_xor(q, 4, 64);
    q += __shfl_xor(q, 8, 64);
    q += __shfl_xor(q, 16, 64);
    q += __shfl_xor(q, 32, 64);
    if (i == 0) fwd_out[b] = (float)ktot * LN2F + logf(q);
#undef SUBSTEP
#undef MV4
}

// Gold path score: fully parallel over t (lane-strided).
__global__ __launch_bounds__(64) void crf_gold_kernel(
    const float* __restrict__ feats,
    const float* __restrict__ transitions,
    const int* __restrict__ tags,     // (B,T)
    const int* __restrict__ lengths,  // (B,)
    float* __restrict__ gold_out)     // (B,)
{
    const int b = blockIdx.x;
    const int lane = threadIdx.x;
    const int len = lengths[b];
    const int* tb = tags + b * Tt;
    const float* fb = feats + (size_t)b * Tt * Kk;

    float acc = 0.f;
    for (int t = lane; t < len; t += 64) {
        const int tg = tb[t];
        const int prev = (t == 0) ? START_TAG : tb[t - 1];
        acc += transitions[tg * Kk + prev];  // score prev -> tg
        acc += fb[t * Kk + tg];              // emission
    }
    if (lane == 0) acc += transitions[STOP_TAG * Kk + tb[len - 1]];  // last -> STOP
#pragma unroll
    for (int off = 32; off >= 1; off >>= 1) acc += __shfl_xor(acc, off, 64);
    if (lane == 0) gold_out[b] = acc;
}

__global__ __launch_bounds__(512) void crf_reduce_kernel(
    const float* __restrict__ fwd, const float* __restrict__ gold,
    float* __restrict__ out)
{
    const int i = threadIdx.x;  // 0..511
    float v = fwd[i] - gold[i];
#pragma unroll
    for (int off = 32; off >= 1; off >>= 1) v += __shfl_xor(v, off, 64);
    __shared__ float ws[8];
    if ((i & 63) == 0) ws[i >> 6] = v;
    __syncthreads();
    if (i < 8) {
        float s = ws[i];
#pragma unroll
        for (int off = 4; off >= 1; off >>= 1) s += __shfl_xor(s, off, 8);
        if (i == 0) out[0] = s * (1.0f / (float)Bb);
    }
}

extern "C" void kernel_launch(void* const* d_in, const int* in_sizes, int n_in,
                              void* d_out, int out_size, void* d_ws, size_t ws_size,
                              hipStream_t stream) {
    const float* feats = (const float*)d_in[0];
    const float* trans = (const float*)d_in[1];
    const int* tags = (const int*)d_in[2];
    const int* lengths = (const int*)d_in[3];
    float* out = (float*)d_out;
    float* fwd = (float*)d_ws;
    float* gold = fwd + Bb;

    crf_gold_kernel<<<Bb, 64, 0, stream>>>(feats, trans, tags, lengths, gold);
    crf_forward_kernel<<<Bb, 64, 0, stream>>>(feats, trans, lengths, fwd);
    crf_reduce_kernel<<<1, 512, 0, stream>>>(fwd, gold, out);
}

// Round 3
// 200.442 us; speedup vs baseline: 1.6713x; 1.1025x over previous
//
#include <hip/hip_runtime.h>
#include <hip/hip_bf16.h>

#define Bb 512
#define Tt 512
#define Kk 64
#define START_TAG 62
#define STOP_TAG 63
#define LN2F 0.69314718055994530942f

// Forward algorithm in exp-space, one 64-lane wave per sequence.
// Lane i owns output tag i; exp(transitions[i][:]) lives in 16 NAMED float4
// VGPR quads (T0..T15). __launch_bounds__(64, 1) is ESSENTIAL: without the
// min-waves=1 arg the compiler targets 8 waves/EU -> 64-VGPR cap -> spills
// the transition matrix to scratch (round 1/2: VGPR_Count=60/64, ~1000
// cyc/step). Rescale every 4 steps by an exact power of two derived from
// lane 0's exponent (v_readlane -> all-scalar, no cross-lane butterfly).
__global__ __launch_bounds__(64, 1) void crf_forward_kernel(
    const float* __restrict__ feats,        // (B,T,K)
    const float* __restrict__ transitions,  // (K,K), trans[i,j] = score j->i
    const int* __restrict__ lengths,        // (B,)
    float* __restrict__ fwd_out)            // (B,)
{
    const int b = blockIdx.x;
    const int i = threadIdx.x;  // 0..63
    __shared__ __align__(16) float sa[Kk];
    const float4* sa4 = reinterpret_cast<const float4*>(sa);

    const float4* tr4 = reinterpret_cast<const float4*>(transitions + i * Kk);
#define LOADT(n) float4 T##n = tr4[n];                                   \
    T##n.x = __expf(T##n.x); T##n.y = __expf(T##n.y);                    \
    T##n.z = __expf(T##n.z); T##n.w = __expf(T##n.w);
    LOADT(0)  LOADT(1)  LOADT(2)  LOADT(3)
    LOADT(4)  LOADT(5)  LOADT(6)  LOADT(7)
    LOADT(8)  LOADT(9)  LOADT(10) LOADT(11)
    LOADT(12) LOADT(13) LOADT(14) LOADT(15)
#undef LOADT
    const float etstop = __expf(transitions[STOP_TAG * Kk + i]);

    const int len = lengths[b];
    const float* fb = feats + (size_t)b * Tt * Kk + i;

    // init: exp(alpha) = 1 at START, 0 elsewhere; scale s = 0 (ktot=0)
    sa[i] = (i == START_TAG) ? 1.0f : 0.0f;
    __builtin_amdgcn_wave_barrier();

    int ktot = 0;        // applied log2-scale (integer, exact)
    float s_pend = 1.0f; // pending 2^-k, folded into next group's first emit
    float pcur = (i == START_TAG) ? 1.0f : 0.0f;  // lane-local copy of sa[i]

    // prefetch emits for t = 0..3 (always in-bounds: T = 512 rows per seq)
    float e0 = fb[0], e1 = fb[Kk], e2 = fb[2 * Kk], e3 = fb[3 * Kk];

    const int nfull = len & ~3;

#define MV4(n, A0, A1, A2, A3) { float4 a_ = sa4[n];                     \
    A0 = fmaf(a_.x, T##n.x, A0); A1 = fmaf(a_.y, T##n.y, A1);            \
    A2 = fmaf(a_.z, T##n.z, A2); A3 = fmaf(a_.w, T##n.w, A3); }

#define SUBSTEP(EE) {                                                    \
    float q0=0.f,q1=0.f,q2=0.f,q3=0.f,q4=0.f,q5=0.f,q6=0.f,q7=0.f;       \
    MV4(0,q0,q1,q2,q3)  MV4(1,q4,q5,q6,q7)                               \
    MV4(2,q0,q1,q2,q3)  MV4(3,q4,q5,q6,q7)                               \
    MV4(4,q0,q1,q2,q3)  MV4(5,q4,q5,q6,q7)                               \
    MV4(6,q0,q1,q2,q3)  MV4(7,q4,q5,q6,q7)                               \
    MV4(8,q0,q1,q2,q3)  MV4(9,q4,q5,q6,q7)                               \
    MV4(10,q0,q1,q2,q3) MV4(11,q4,q5,q6,q7)                              \
    MV4(12,q0,q1,q2,q3) MV4(13,q4,q5,q6,q7)                              \
    MV4(14,q0,q1,q2,q3) MV4(15,q4,q5,q6,q7)                              \
    pcur = (((q0+q1)+(q2+q3)) + ((q4+q5)+(q6+q7))) * (EE);               \
    sa[i] = pcur;                                                        \
    __builtin_amdgcn_wave_barrier(); }

    for (int t = 0; t < nfull; t += 4) {
        // emit exps off the critical path; fold pending scale into ee0
        float ee0 = __expf(e0) * s_pend;
        float ee1 = __expf(e1);
        float ee2 = __expf(e2);
        float ee3 = __expf(e3);
        // prefetch next group (clamped; values past len are never used)
        const int tn = t + 4;
        const int c0 = (tn     < Tt) ? tn     : Tt - 1;
        const int c1 = (tn + 1 < Tt) ? tn + 1 : Tt - 1;
        const int c2 = (tn + 2 < Tt) ? tn + 2 : Tt - 1;
        const int c3 = (tn + 3 < Tt) ? tn + 3 : Tt - 1;
        e0 = fb[c0 * Kk]; e1 = fb[c1 * Kk]; e2 = fb[c2 * Kk]; e3 = fb[c3 * Kk];

        SUBSTEP(ee0) SUBSTEP(ee1) SUBSTEP(ee2) SUBSTEP(ee3)

        // rescale by exact 2^-k, k = exponent(alpha_lane0). Any wave-uniform
        // pow2 estimate works (rescale is relative; inter-lane alpha spread
        // <= ~2^23 << fp32 headroom). All-scalar: no cross-lane butterfly.
        const unsigned m_bits =
            (unsigned)__builtin_amdgcn_readlane(__float_as_int(pcur), 0);
        const int k = (int)((m_bits >> 23) & 255) - 127;
        ktot += k;
        s_pend = __uint_as_float((unsigned)(127 - k) << 23);
    }

    // tail (<= 3 steps; growth stays far below fp32 max without rescale)
    if (nfull < len) {
        float ee = __expf(e0) * s_pend;
        SUBSTEP(ee)
        s_pend = 1.0f;
        if (nfull + 1 < len) { float ee1 = __expf(e1); SUBSTEP(ee1) }
        if (nfull + 2 < len) { float ee2 = __expf(e2); SUBSTEP(ee2) }
    }

    // terminal: log sum_i exp(alpha_i) * eT[STOP,i]  (+ applied scales)
    float q = pcur * s_pend * etstop;
    q += __shfl_xor(q, 1, 64);
    q += __shfl_xor(q, 2, 64);
    q += __shfl_xor(q, 4, 64);
    q += __shfl_xor(q, 8, 64);
    q += __shfl_xor(q, 16, 64);
    q += __shfl_xor(q, 32, 64);
    if (i == 0) fwd_out[b] = (float)ktot * LN2F + logf(q);
#undef SUBSTEP
#undef MV4
}

// Gold path score: fully parallel over t (lane-strided).
__global__ __launch_bounds__(64) void crf_gold_kernel(
    const float* __restrict__ feats,
    const float* __restrict__ transitions,
    const int* __restrict__ tags,     // (B,T)
    const int* __restrict__ lengths,  // (B,)
    float* __restrict__ gold_out)     // (B,)
{
    const int b = blockIdx.x;
    const int lane = threadIdx.x;
    const int len = lengths[b];
    const int* tb = tags + b * Tt;
    const float* fb = feats + (size_t)b * Tt * Kk;

    float acc = 0.f;
    for (int t = lane; t < len; t += 64) {
        const int tg = tb[t];
        const int prev = (t == 0) ? START_TAG : tb[t - 1];
        acc += transitions[tg * Kk + prev];  // score prev -> tg
        acc += fb[t * Kk + tg];              // emission
    }
    if (lane == 0) acc += transitions[STOP_TAG * Kk + tb[len - 1]];  // last -> STOP
#pragma unroll
    for (int off = 32; off >= 1; off >>= 1) acc += __shfl_xor(acc, off, 64);
    if (lane == 0) gold_out[b] = acc;
}

__global__ __launch_bounds__(512) void crf_reduce_kernel(
    const float* __restrict__ fwd, const float* __restrict__ gold,
    float* __restrict__ out)
{
    const int i = threadIdx.x;  // 0..511
    float v = fwd[i] - gold[i];
#pragma unroll
    for (int off = 32; off >= 1; off >>= 1) v += __shfl_xor(v, off, 64);
    __shared__ float ws[8];
    if ((i & 63) == 0) ws[i >> 6] = v;
    __syncthreads();
    if (i < 8) {
        float s = ws[i];
#pragma unroll
        for (int off = 4; off >= 1; off >>= 1) s += __shfl_xor(s, off, 8);
        if (i == 0) out[0] = s * (1.0f / (float)Bb);
    }
}

extern "C" void kernel_launch(void* const* d_in, const int* in_sizes, int n_in,
                              void* d_out, int out_size, void* d_ws, size_t ws_size,
                              hipStream_t stream) {
    const float* feats = (const float*)d_in[0];
    const float* trans = (const float*)d_in[1];
    const int* tags = (const int*)d_in[2];
    const int* lengths = (const int*)d_in[3];
    float* out = (float*)d_out;
    float* fwd = (float*)d_ws;
    float* gold = fwd + Bb;

    crf_gold_kernel<<<Bb, 64, 0, stream>>>(feats, trans, tags, lengths, gold);
    crf_forward_kernel<<<Bb, 64, 0, stream>>>(feats, trans, lengths, fwd);
    crf_reduce_kernel<<<1, 512, 0, stream>>>(fwd, gold, out);
}